// Round 16
// baseline (167.128 us; speedup 1.0000x reference)
//
#include <hip/hip_runtime.h>

#define HD      64
#define VOC     64
#define HALF    32
#define BATCH   128
#define SEQLEN  2048

// ---------------------------------------------------------------------------
// Kernel 1: per-vocab table (unchanged; verified R1-R15).
// ---------------------------------------------------------------------------
__global__ __launch_bounds__(64) void build_table_kernel(
    const float* __restrict__ embed, const float* __restrict__ W1, const float* __restrict__ b1,
    const float* __restrict__ W2,    const float* __restrict__ b2,
    const float* __restrict__ ln_g,  const float* __restrict__ ln_b,
    const float* __restrict__ Ws,    const float* __restrict__ bs,
    const float* __restrict__ We,    const float* __restrict__ be,
    float* __restrict__ Ktab, float* __restrict__ rden)
{
    const int v = blockIdx.x;
    const int j = threadIdx.x;

    __shared__ float e_s[64];
    __shared__ float u_s[128];
    __shared__ float h_s[64];

    float e = embed[v*HD + j];
    e_s[j] = e;
    __syncthreads();

    float u0 = b1[j], u1 = b1[j + 64];
    #pragma unroll
    for (int i = 0; i < 64; ++i) {
        float ei = e_s[i];
        u0 = fmaf(ei, W1[i*128 + j],      u0);
        u1 = fmaf(ei, W1[i*128 + 64 + j], u1);
    }
    u_s[j]      = fmaxf(u0, 0.f);
    u_s[j + 64] = fmaxf(u1, 0.f);
    __syncthreads();

    float ff = b2[j];
    #pragma unroll
    for (int c = 0; c < 128; ++c) ff = fmaf(u_s[c], W2[c*64 + j], ff);

    float x = e + ff;
    float mu = x;
    #pragma unroll
    for (int m = 32; m; m >>= 1) mu += __shfl_xor(mu, m, 64);
    mu *= (1.f / 64.f);
    float d = x - mu;
    float var = d * d;
    #pragma unroll
    for (int m = 32; m; m >>= 1) var += __shfl_xor(var, m, 64);
    var *= (1.f / 64.f);
    float h = d * rsqrtf(var + 1e-5f) * ln_g[j] + ln_b[j];
    h_s[j] = h;
    __syncthreads();

    const int mm = j >> 5;
    const int jj = j & 31;
    const float* W  = mm ? We : Ws;
    float acc = mm ? be[jj] : bs[jj];
    #pragma unroll
    for (int i = 0; i < 64; ++i) acc = fmaf(h_s[i], W[i*32 + jj], acc);
    Ktab[(mm*VOC + v)*HALF + jj] = acc;

    float s = acc * acc;
    #pragma unroll
    for (int m = 16; m; m >>= 1) s += __shfl_xor(s, m, 32);
    if (jj == 0) rden[mm*VOC + v] = 1.f / (s + 1e-6f);
}

// ---------------------------------------------------------------------------
// Kernel 1b: gram table G[mm][v1][v2] = k_{v1} . k_{v2}. (unchanged R8)
// ---------------------------------------------------------------------------
__global__ __launch_bounds__(256) void gram_kernel(
    const float* __restrict__ Ktab, float* __restrict__ Gtab)
{
    const int mm  = blockIdx.x;
    const int tid = threadIdx.x;
    const int v2  = tid & 63;
    const int qq  = tid >> 6;

    __shared__ __align__(16) float kt[VOC * HALF];
    {
        float4* d = (float4*)kt;
        const float4* s = (const float4*)(Ktab + mm*VOC*HALF);
        d[tid] = s[tid];
        d[tid + 256] = s[tid + 256];
    }
    __syncthreads();

    float4 r[8];
    #pragma unroll
    for (int j = 0; j < 8; ++j) r[j] = *(const float4*)&kt[v2*32 + 4*j];

    for (int v1 = qq*16; v1 < qq*16 + 16; ++v1) {
        float s0 = 0.f, s1 = 0.f, s2 = 0.f, s3 = 0.f;
        #pragma unroll
        for (int j = 0; j < 8; ++j) {
            float4 a = *(const float4*)&kt[v1*32 + 4*j];
            s0 = fmaf(a.x, r[j].x, s0);
            s1 = fmaf(a.y, r[j].y, s1);
            s2 = fmaf(a.z, r[j].z, s2);
            s3 = fmaf(a.w, r[j].w, s3);
        }
        Gtab[(mm*VOC + v1)*VOC + v2] = (s0 + s1) + (s2 + s3);
    }
}

// ---------------------------------------------------------------------------
// Kernel 2: chunked backward scan, pipelined rounds (R13 skeleton verbatim).
// R16 (ONE change): the R-matrix stays in REGISTERS. Lane col computes column
// col of R (r_[t] = c_col * G[v_t, v_col]); substitution step s reads R[t][s]
// from lane s via v_readlane (compile-time s,t) -> SGPR, fma with SGPR operand.
// Deletes the Rcs LDS array: -16 writes, -~140 b128 reads per chunk on the
// shared LDS pipe; readlane work runs on each solver wave's own SIMD.
// Arithmetic value-identical to R12/R13's column solve.
// ---------------------------------------------------------------------------
__global__ __launch_bounds__(256, 1) void chunk_scan_kernel(
    const int*   __restrict__ seq,
    const float* __restrict__ Ktab,
    const float* __restrict__ rden,
    const float* __restrict__ Gtab,
    float*       __restrict__ ctxg)
{
    const int bm   = blockIdx.x;      // 0..255
    const int b    = bm >> 1;
    const int mm   = bm & 1;
    const int tid  = threadIdx.x;
    const int lane = tid & 63;
    const int wave = tid >> 6;
    const int col  = lane & 31;       // 0..31
    const int half = lane >> 5;       // 0..1

    __shared__ __align__(16) float ktp[VOC * 33];      // padded kt
    __shared__ __align__(16) float Gp [VOC * 65];      // padded gram
    __shared__ float rd_s[VOC];
    __shared__ int   sq[SEQLEN];
    __shared__ __align__(16) float Wl [2][3][32 * 36]; // W rows, double-buffered
    __shared__ __align__(16) float Kd [2][3][32 * 36]; // Kd[c*36+t] = k_{v_t}[c]
    __shared__ __align__(16) float carr[2][3][32];
    __shared__ __align__(16) float warr[2][3][32];
    __shared__ __align__(16) float z_l[32];
    __shared__ float a_l[32], b_l[32];

    // ---- stage tables (verbatim R13) ----
    for (int idx = tid; idx < VOC*HALF; idx += 256) {
        int v = idx >> 5, c = idx & 31;
        ktp[v*33 + c] = Ktab[mm*VOC*HALF + idx];
    }
    for (int idx = tid; idx < VOC*VOC; idx += 256) {
        int v1 = idx >> 6, v2 = idx & 63;
        Gp[v1*65 + v2] = Gtab[mm*VOC*VOC + idx];
    }
    if (tid < VOC) rd_s[tid] = rden[mm*VOC + tid];
    {
        const int4* S = (const int4*)(seq + b*SEQLEN);
        int4* D = (int4*)sq;
        D[tid] = S[tid];
        D[tid + 256] = S[tid + 256];
    }
    __syncthreads();

    if (tid < 32) z_l[tid] = ktp[sq[SEQLEN-1]*33 + tid];
    __syncthreads();

    const float inv = 1.0f / (float)SEQLEN;

    // ---- solver: chunk ck into buffer p, slot ----
    auto SOLVE = [&](int ck, int p, int slot) {
        const int T0 = ck << 5;

        // per-chunk scalars (verbatim R13 write pattern)
        if (lane < 32) {
            int tg = T0 + lane;
            int v  = sq[tg];
            float wgt = mm ? (float)(tg + 1) * inv : 1.0f;
            if (tg == SEQLEN-1) wgt = 0.f;
            carr[p][slot][lane] = rd_s[v] * wgt;
            warr[p][slot][lane] = wgt;
        }
        __builtin_amdgcn_sched_barrier(0);

        // chunk token ids (wave-uniform int4 reads)
        int vo[32];
        #pragma unroll
        for (int q = 0; q < 8; ++q) {
            int4 vv = *(const int4*)&sq[T0 + 4*q];
            vo[4*q+0] = vv.x; vo[4*q+1] = vv.y;
            vo[4*q+2] = vv.z; vo[4*q+3] = vv.w;
        }

        // this lane's column scalars (computed locally; same formula as carr)
        const int vs = sq[T0 + col];
        float wgt = mm ? (float)(T0 + col + 1) * inv : 1.0f;
        if (T0 + col == SEQLEN-1) wgt = 0.f;
        const float cs = rd_s[vs] * wgt;

        // R column col IN REGISTERS: r_[t] = c_col * G[v_t, v_col]
        // (values for t >= col exist but are never read via readlane)
        float r_[32];
        #pragma unroll
        for (int t = 0; t < 32; ++t)
            r_[t] = cs * Gp[vo[t]*65 + vs];

        // column-per-lane init; publish Kd rows BEFORE substitution mutates w_
        float w_[32];
        #pragma unroll
        for (int t = 0; t < 32; ++t)
            w_[t] = ktp[vo[t]*33 + col];
        if (lane < 32) {
            #pragma unroll
            for (int q = 0; q < 8; ++q) {
                float4 f;
                f.x = w_[4*q+0]; f.y = w_[4*q+1];
                f.z = w_[4*q+2]; f.w = w_[4*q+3];
                *(float4*)&Kd[p][slot][col*36 + 4*q] = f;
            }
        }

        // backward substitution: w_[t] -= R[t][s] * w_[s], t < s.
        // R[t][s] fetched from lane s via readlane (compile-time s,t).
        #pragma unroll
        for (int s = 31; s >= 1; --s) {
            const float ws = w_[s];
            #pragma unroll
            for (int t = 0; t < s; ++t) {
                float Rts = __int_as_float(
                    __builtin_amdgcn_readlane(__float_as_int(r_[t]), s));
                w_[t] = fmaf(-ws, Rts, w_[t]);
            }
        }

        // publish W rows (lanes 0-31; lanes 32-63 hold identical mirrors)
        if (lane < 32) {
            #pragma unroll
            for (int t = 0; t < 32; ++t)
                Wl[p][slot][t*36 + col] = w_[t];
        }
    };

    float ctx_r = 0.f;

    // ---- applier (verbatim R13) ----
    auto APPLY = [&](int p, int slot) {
        float pg0 = 0.f, pg1 = 0.f, pg2 = 0.f, pg3 = 0.f;
        const float* wrow = &Wl[p][slot][col*36];
        #pragma unroll
        for (int q = 0; q < 8; ++q) {
            float4 wr = *(const float4*)&wrow[4*q];
            float4 zv = *(const float4*)&z_l[4*q];
            pg0 = fmaf(wr.x, zv.x, pg0);
            pg1 = fmaf(wr.y, zv.y, pg1);
            pg2 = fmaf(wr.z, zv.z, pg2);
            pg3 = fmaf(wr.w, zv.w, pg3);
        }
        float d  = (pg0 + pg1) + (pg2 + pg3);
        float al = carr[p][slot][col] * d;
        float bl = warr[p][slot][col] * d;
        if (lane < 32) { a_l[col] = al; b_l[col] = bl; }
        __builtin_amdgcn_sched_barrier(0);

        float pz0 = 0.f, pz1 = 0.f, pc0 = 0.f, pc1 = 0.f;
        const float* krow = &Kd[p][slot][col*36];
        #pragma unroll
        for (int q = 0; q < 8; ++q) {
            float4 k4 = *(const float4*)&krow[4*q];
            float4 a4 = *(const float4*)&a_l[4*q];
            float4 b4 = *(const float4*)&b_l[4*q];
            pz0 = fmaf(a4.x, k4.x, pz0);
            pz1 = fmaf(a4.y, k4.y, pz1);
            pz0 = fmaf(a4.z, k4.z, pz0);
            pz1 = fmaf(a4.w, k4.w, pz1);
            pc0 = fmaf(b4.x, k4.x, pc0);
            pc1 = fmaf(b4.y, k4.y, pc1);
            pc0 = fmaf(b4.z, k4.z, pc0);
            pc1 = fmaf(b4.w, k4.w, pc1);
        }
        if (lane < 32) z_l[col] = z_l[col] - (pz0 + pz1);
        ctx_r += (pc0 + pc1);
        __builtin_amdgcn_sched_barrier(0);
    };

    // ---- prologue: solve set 0 (chunks 61,62,63) into buffer 0 ----
    if (wave > 0) SOLVE(61 + (wave - 1), 0, wave - 1);
    __syncthreads();

    // ---- pipelined rounds: apply set r (buf r&1) || solve set r+1 ----
    for (int r = 0; r <= 21; ++r) {
        const int baseA = 61 - 3*r;
        if (wave == 0) {
            #pragma unroll
            for (int j = 2; j >= 0; --j) {
                if (baseA + j >= 0) APPLY(r & 1, j);
            }
        } else if (r < 21) {
            int ck = (61 - 3*(r+1)) + (wave - 1);
            if (ck >= 0) SOLVE(ck, (r+1) & 1, wave - 1);
        }
        __syncthreads();
    }

    if (tid < 32) ctxg[b*64 + mm*32 + tid] = ctx_r;
}

// ---------------------------------------------------------------------------
// Kernel 3: out = ctx @ Wo + bo.
// ---------------------------------------------------------------------------
__global__ __launch_bounds__(64) void out_kernel(
    const float* __restrict__ ctx, const float* __restrict__ Wo,
    const float* __restrict__ bo,  float* __restrict__ out)
{
    const int b = blockIdx.x;
    const int o = threadIdx.x;
    float acc = bo[o];
    #pragma unroll
    for (int i = 0; i < 64; ++i) acc = fmaf(ctx[b*64 + i], Wo[i*64 + o], acc);
    out[b*64 + o] = acc;
}

extern "C" void kernel_launch(void* const* d_in, const int* in_sizes, int n_in,
                              void* d_out, int out_size, void* d_ws, size_t ws_size,
                              hipStream_t stream)
{
    const int*   seq   = (const int*)  d_in[0];
    const float* embed = (const float*)d_in[1];
    const float* W1    = (const float*)d_in[2];
    const float* b1    = (const float*)d_in[3];
    const float* W2    = (const float*)d_in[4];
    const float* b2    = (const float*)d_in[5];
    const float* ln_g  = (const float*)d_in[6];
    const float* ln_b  = (const float*)d_in[7];
    const float* Ws    = (const float*)d_in[8];
    const float* bs    = (const float*)d_in[9];
    const float* We    = (const float*)d_in[10];
    const float* be    = (const float*)d_in[11];
    const float* Wo    = (const float*)d_in[12];
    const float* bo    = (const float*)d_in[13];
    float* out = (float*)d_out;

    float* Ktab = (float*)d_ws;                 // 2*64*32
    float* rden = Ktab + 2*VOC*HALF;            // 2*64
    float* Gtab = rden + 2*VOC;                 // 2*64*64
    float* ctx  = Gtab + 2*VOC*VOC;             // 128*64

    build_table_kernel<<<VOC, 64, 0, stream>>>(embed, W1, b1, W2, b2, ln_g, ln_b,
                                               Ws, bs, We, be, Ktab, rden);
    gram_kernel<<<2, 256, 0, stream>>>(Ktab, Gtab);
    chunk_scan_kernel<<<BATCH*2, 256, 0, stream>>>(seq, Ktab, rden, Gtab, ctx);
    out_kernel<<<BATCH, 64, 0, stream>>>(ctx, Wo, bo, out);
}

// Round 17
// 65.093 us; speedup vs baseline: 2.5675x; 2.5675x over previous
//
#include <hip/hip_runtime.h>

#define HD      64
#define VOC     64
#define HALF    32
#define BATCH   128
#define SEQLEN  2048

// ---------------------------------------------------------------------------
// Kernel 1: per-vocab table (unchanged; verified R1-R16).
// ---------------------------------------------------------------------------
__global__ __launch_bounds__(64) void build_table_kernel(
    const float* __restrict__ embed, const float* __restrict__ W1, const float* __restrict__ b1,
    const float* __restrict__ W2,    const float* __restrict__ b2,
    const float* __restrict__ ln_g,  const float* __restrict__ ln_b,
    const float* __restrict__ Ws,    const float* __restrict__ bs,
    const float* __restrict__ We,    const float* __restrict__ be,
    float* __restrict__ Ktab, float* __restrict__ rden)
{
    const int v = blockIdx.x;
    const int j = threadIdx.x;

    __shared__ float e_s[64];
    __shared__ float u_s[128];
    __shared__ float h_s[64];

    float e = embed[v*HD + j];
    e_s[j] = e;
    __syncthreads();

    float u0 = b1[j], u1 = b1[j + 64];
    #pragma unroll
    for (int i = 0; i < 64; ++i) {
        float ei = e_s[i];
        u0 = fmaf(ei, W1[i*128 + j],      u0);
        u1 = fmaf(ei, W1[i*128 + 64 + j], u1);
    }
    u_s[j]      = fmaxf(u0, 0.f);
    u_s[j + 64] = fmaxf(u1, 0.f);
    __syncthreads();

    float ff = b2[j];
    #pragma unroll
    for (int c = 0; c < 128; ++c) ff = fmaf(u_s[c], W2[c*64 + j], ff);

    float x = e + ff;
    float mu = x;
    #pragma unroll
    for (int m = 32; m; m >>= 1) mu += __shfl_xor(mu, m, 64);
    mu *= (1.f / 64.f);
    float d = x - mu;
    float var = d * d;
    #pragma unroll
    for (int m = 32; m; m >>= 1) var += __shfl_xor(var, m, 64);
    var *= (1.f / 64.f);
    float h = d * rsqrtf(var + 1e-5f) * ln_g[j] + ln_b[j];
    h_s[j] = h;
    __syncthreads();

    const int mm = j >> 5;
    const int jj = j & 31;
    const float* W  = mm ? We : Ws;
    float acc = mm ? be[jj] : bs[jj];
    #pragma unroll
    for (int i = 0; i < 64; ++i) acc = fmaf(h_s[i], W[i*32 + jj], acc);
    Ktab[(mm*VOC + v)*HALF + jj] = acc;

    float s = acc * acc;
    #pragma unroll
    for (int m = 16; m; m >>= 1) s += __shfl_xor(s, m, 32);
    if (jj == 0) rden[mm*VOC + v] = 1.f / (s + 1e-6f);
}

// ---------------------------------------------------------------------------
// Kernel 1b: gram table G[mm][v1][v2] = k_{v1} . k_{v2}. (unchanged R8)
// ---------------------------------------------------------------------------
__global__ __launch_bounds__(256) void gram_kernel(
    const float* __restrict__ Ktab, float* __restrict__ Gtab)
{
    const int mm  = blockIdx.x;
    const int tid = threadIdx.x;
    const int v2  = tid & 63;
    const int qq  = tid >> 6;

    __shared__ __align__(16) float kt[VOC * HALF];
    {
        float4* d = (float4*)kt;
        const float4* s = (const float4*)(Ktab + mm*VOC*HALF);
        d[tid] = s[tid];
        d[tid + 256] = s[tid + 256];
    }
    __syncthreads();

    float4 r[8];
    #pragma unroll
    for (int j = 0; j < 8; ++j) r[j] = *(const float4*)&kt[v2*32 + 4*j];

    for (int v1 = qq*16; v1 < qq*16 + 16; ++v1) {
        float s0 = 0.f, s1 = 0.f, s2 = 0.f, s3 = 0.f;
        #pragma unroll
        for (int j = 0; j < 8; ++j) {
            float4 a = *(const float4*)&kt[v1*32 + 4*j];
            s0 = fmaf(a.x, r[j].x, s0);
            s1 = fmaf(a.y, r[j].y, s1);
            s2 = fmaf(a.z, r[j].z, s2);
            s3 = fmaf(a.w, r[j].w, s3);
        }
        Gtab[(mm*VOC + v1)*VOC + v2] = (s0 + s1) + (s2 + s3);
    }
}

// ---------------------------------------------------------------------------
// Kernel 2: chunked backward scan, pipelined rounds (R13 skeleton).
// R17: (a) each solver wave solves TWO chunks via lane halves (half-split
// proven correct in R15; mirror half was redundant) -> chunk-sets of 6,
// 11 rounds; (b) Gram read from GLOBAL in the Rcs build (L2-resident 32KB)
// to fit LDS. APPLY is verbatim R13. Solve arithmetic verbatim R12 per half.
// ---------------------------------------------------------------------------
__global__ __launch_bounds__(256, 1) void chunk_scan_kernel(
    const int*   __restrict__ seq,
    const float* __restrict__ Ktab,
    const float* __restrict__ rden,
    const float* __restrict__ Gtab,
    float*       __restrict__ ctxg)
{
    const int bm   = blockIdx.x;      // 0..255
    const int b    = bm >> 1;
    const int mm   = bm & 1;
    const int tid  = threadIdx.x;
    const int lane = tid & 63;
    const int wave = tid >> 6;
    const int col  = lane & 31;       // 0..31
    const int half = lane >> 5;       // 0..1 -> which chunk of the wave's pair

    __shared__ __align__(16) float ktp[VOC * 33];      // padded kt (8.4 KB)
    __shared__ float rd_s[VOC];
    __shared__ int   sq[SEQLEN];                       // 8 KB
    __shared__ __align__(16) float Wl [2][6][32 * 36]; // 55.3 KB
    __shared__ __align__(16) float Kd [2][6][32 * 36]; // 55.3 KB
    __shared__ __align__(16) float Rcs[6][32 * 36];    // 27.6 KB solver scratch
    __shared__ __align__(16) float carr[2][6][32];
    __shared__ __align__(16) float warr[2][6][32];
    __shared__ __align__(16) float z_l[32];
    __shared__ float a_l[32], b_l[32];

    const float* Gq = Gtab + (size_t)mm * VOC * VOC;   // global gram, L2-resident

    // ---- stage tables ----
    for (int idx = tid; idx < VOC*HALF; idx += 256) {
        int v = idx >> 5, c = idx & 31;
        ktp[v*33 + c] = Ktab[mm*VOC*HALF + idx];
    }
    if (tid < VOC) rd_s[tid] = rden[mm*VOC + tid];
    {
        const int4* S = (const int4*)(seq + b*SEQLEN);
        int4* D = (int4*)sq;
        D[tid] = S[tid];
        D[tid + 256] = S[tid + 256];
    }
    __syncthreads();

    if (tid < 32) z_l[tid] = ktp[sq[SEQLEN-1]*33 + tid];
    __syncthreads();

    const float inv = 1.0f / (float)SEQLEN;

    // ---- solver: 2 chunks per wave (half -> slot); R12 math per half ----
    auto SOLVE = [&](int base, int p) {
        const int slot = (wave - 1)*2 + half;
        const int ck   = base + slot;
        const bool act = (ck >= 0);
        const int T0   = act ? (ck << 5) : 0;      // clamp: no OOB reads

        // per-lane scalars for key t=col of this chunk (R12/R16-verified formula)
        const int vs = sq[T0 + col];
        float wgt = mm ? (float)(T0 + col + 1) * inv : 1.0f;
        if (T0 + col == SEQLEN-1) wgt = 0.f;
        const float cs = rd_s[vs] * wgt;
        if (act) {
            carr[p][slot][col] = cs;
            warr[p][slot][col] = wgt;
        }

        // chunk token ids (uniform per half): 8 int4 reads
        int vo[32];
        #pragma unroll
        for (int q = 0; q < 8; ++q) {
            int4 vv = *(const int4*)&sq[T0 + 4*q];
            vo[4*q+0] = vv.x; vo[4*q+1] = vv.y;
            vo[4*q+2] = vv.z; vo[4*q+3] = vv.w;
        }
        __builtin_amdgcn_sched_barrier(0);

        // Rcs column col from GLOBAL gram (off-chain VMEM batch, L2 hits):
        // Rcs[s=col][t] = (t < col) ? c_col * G[v_t, v_col] : 0
        #pragma unroll
        for (int i = 0; i < 32; ++i) {
            float g = Gq[vo[i]*VOC + vs];
            Rcs[slot][col*36 + i] = (i < col) ? cs * g : 0.f;
        }
        __builtin_amdgcn_sched_barrier(0);

        // column-per-lane init; publish Kd rows BEFORE substitution mutates w_
        float w_[32];
        #pragma unroll
        for (int t = 0; t < 32; ++t)
            w_[t] = ktp[vo[t]*33 + col];
        if (act) {
            #pragma unroll
            for (int q = 0; q < 8; ++q) {
                float4 f;
                f.x = w_[4*q+0]; f.y = w_[4*q+1];
                f.z = w_[4*q+2]; f.w = w_[4*q+3];
                *(float4*)&Kd[p][slot][col*36 + 4*q] = f;
            }
        }

        // backward substitution (verbatim R12)
        #pragma unroll
        for (int s = 31; s >= 1; --s) {
            const float ws = w_[s];
            const int nq = (s + 3) >> 2;
            #pragma unroll
            for (int q = 0; q < nq; ++q) {
                float4 rc = *(const float4*)&Rcs[slot][s*36 + 4*q];
                w_[4*q+0] = fmaf(-ws, rc.x, w_[4*q+0]);
                w_[4*q+1] = fmaf(-ws, rc.y, w_[4*q+1]);
                w_[4*q+2] = fmaf(-ws, rc.z, w_[4*q+2]);
                w_[4*q+3] = fmaf(-ws, rc.w, w_[4*q+3]);
            }
        }

        if (act) {
            #pragma unroll
            for (int t = 0; t < 32; ++t)
                Wl[p][slot][t*36 + col] = w_[t];
        }
    };

    float ctx_r = 0.f;

    // ---- applier (verbatim R13) ----
    auto APPLY = [&](int p, int slot) {
        float pg0 = 0.f, pg1 = 0.f, pg2 = 0.f, pg3 = 0.f;
        const float* wrow = &Wl[p][slot][col*36];
        #pragma unroll
        for (int q = 0; q < 8; ++q) {
            float4 wr = *(const float4*)&wrow[4*q];
            float4 zv = *(const float4*)&z_l[4*q];
            pg0 = fmaf(wr.x, zv.x, pg0);
            pg1 = fmaf(wr.y, zv.y, pg1);
            pg2 = fmaf(wr.z, zv.z, pg2);
            pg3 = fmaf(wr.w, zv.w, pg3);
        }
        float d  = (pg0 + pg1) + (pg2 + pg3);
        float al = carr[p][slot][col] * d;
        float bl = warr[p][slot][col] * d;
        if (lane < 32) { a_l[col] = al; b_l[col] = bl; }
        __builtin_amdgcn_sched_barrier(0);

        float pz0 = 0.f, pz1 = 0.f, pc0 = 0.f, pc1 = 0.f;
        const float* krow = &Kd[p][slot][col*36];
        #pragma unroll
        for (int q = 0; q < 8; ++q) {
            float4 k4 = *(const float4*)&krow[4*q];
            float4 a4 = *(const float4*)&a_l[4*q];
            float4 b4 = *(const float4*)&b_l[4*q];
            pz0 = fmaf(a4.x, k4.x, pz0);
            pz1 = fmaf(a4.y, k4.y, pz1);
            pz0 = fmaf(a4.z, k4.z, pz0);
            pz1 = fmaf(a4.w, k4.w, pz1);
            pc0 = fmaf(b4.x, k4.x, pc0);
            pc1 = fmaf(b4.y, k4.y, pc1);
            pc0 = fmaf(b4.z, k4.z, pc0);
            pc1 = fmaf(b4.w, k4.w, pc1);
        }
        if (lane < 32) z_l[col] = z_l[col] - (pz0 + pz1);
        ctx_r += (pc0 + pc1);
        __builtin_amdgcn_sched_barrier(0);
    };

    // ---- prologue: solve set 0 (chunks 58..63) into buffer 0 ----
    if (wave > 0) SOLVE(58, 0);
    __syncthreads();

    // ---- pipelined rounds: apply set r (buf r&1) || solve set r+1 ----
    for (int r = 0; r <= 10; ++r) {
        const int baseA = 58 - 6*r;
        if (wave == 0) {
            #pragma unroll
            for (int j = 5; j >= 0; --j) {
                if (baseA + j >= 0) APPLY(r & 1, j);
            }
        } else if (r < 10) {
            SOLVE(52 - 6*r, (r + 1) & 1);
        }
        __syncthreads();
    }

    if (tid < 32) ctxg[b*64 + mm*32 + tid] = ctx_r;
}

// ---------------------------------------------------------------------------
// Kernel 3: out = ctx @ Wo + bo.
// ---------------------------------------------------------------------------
__global__ __launch_bounds__(64) void out_kernel(
    const float* __restrict__ ctx, const float* __restrict__ Wo,
    const float* __restrict__ bo,  float* __restrict__ out)
{
    const int b = blockIdx.x;
    const int o = threadIdx.x;
    float acc = bo[o];
    #pragma unroll
    for (int i = 0; i < 64; ++i) acc = fmaf(ctx[b*64 + i], Wo[i*64 + o], acc);
    out[b*64 + o] = acc;
}

extern "C" void kernel_launch(void* const* d_in, const int* in_sizes, int n_in,
                              void* d_out, int out_size, void* d_ws, size_t ws_size,
                              hipStream_t stream)
{
    const int*   seq   = (const int*)  d_in[0];
    const float* embed = (const float*)d_in[1];
    const float* W1    = (const float*)d_in[2];
    const float* b1    = (const float*)d_in[3];
    const float* W2    = (const float*)d_in[4];
    const float* b2    = (const float*)d_in[5];
    const float* ln_g  = (const float*)d_in[6];
    const float* ln_b  = (const float*)d_in[7];
    const float* Ws    = (const float*)d_in[8];
    const float* bs    = (const float*)d_in[9];
    const float* We    = (const float*)d_in[10];
    const float* be    = (const float*)d_in[11];
    const float* Wo    = (const float*)d_in[12];
    const float* bo    = (const float*)d_in[13];
    float* out = (float*)d_out;

    float* Ktab = (float*)d_ws;                 // 2*64*32
    float* rden = Ktab + 2*VOC*HALF;            // 2*64
    float* Gtab = rden + 2*VOC;                 // 2*64*64
    float* ctx  = Gtab + 2*VOC*VOC;             // 128*64

    build_table_kernel<<<VOC, 64, 0, stream>>>(embed, W1, b1, W2, b2, ln_g, ln_b,
                                               Ws, bs, We, be, Ktab, rden);
    gram_kernel<<<2, 256, 0, stream>>>(Ktab, Gtab);
    chunk_scan_kernel<<<BATCH*2, 256, 0, stream>>>(seq, Ktab, rden, Gtab, ctx);
    out_kernel<<<BATCH, 64, 0, stream>>>(ctx, Wo, bo, out);
}